// Round 1
// baseline (553.764 us; speedup 1.0000x reference)
//
#include <hip/hip_runtime.h>

#define FDIM 128

// ---------------------------------------------------------------------------
// Kernel 1: row_ptr[i] = lower_bound(rows, i), for i in [0, N]. rows sorted.
// ---------------------------------------------------------------------------
__global__ __launch_bounds__(256) void build_row_ptr_k(const int* __restrict__ rows,
                                                       int E, int N,
                                                       int* __restrict__ rp) {
    int i = blockIdx.x * 256 + threadIdx.x;
    if (i > N) return;
    int lo = 0, hi = E;
    while (lo < hi) {
        int mid = (lo + hi) >> 1;
        if (rows[mid] < i) lo = mid + 1; else hi = mid;
    }
    rp[i] = lo;
}

// ---------------------------------------------------------------------------
// Kernel 2: C[M x 128] = A[M x 128] @ W[128 x 128], f32 vector ALU.
// W staged in LDS (exactly 64KB). A read from global (16-lane broadcast per
// address; tile streams through L1/L2). 256 threads, 8x8 register tile each,
// block tile 128x128, full K=128 resident -> single barrier.
// ---------------------------------------------------------------------------
__global__ __launch_bounds__(256) void gemm_f32_k(const float* __restrict__ A,
                                                  const float* __restrict__ W,
                                                  float* __restrict__ C, int M) {
    __shared__ float Ws[128][128];   // 65536 B
    const int t = threadIdx.x;
    const int row0 = blockIdx.x * 128;

    // stage W: 4096 float4s, 16 per thread, coalesced, conflict-free writes
#pragma unroll
    for (int i = 0; i < 16; ++i) {
        int f = t + i * 256;            // 0..4095
        int k = f >> 5;                 // W row
        int c = (f & 31) << 2;          // W col (float4)
        *(float4*)&Ws[k][c] = *(const float4*)&W[(k << 7) + c];
    }
    __syncthreads();

    const int ty = t >> 4;              // 0..15 -> 8 rows each
    const int tx = t & 15;              // 0..15 -> 8 cols each

    const float* aptr[8];
    int grow[8];
#pragma unroll
    for (int i = 0; i < 8; ++i) {
        int gr = row0 + ty * 8 + i;
        grow[i] = gr;
        if (gr >= M) gr = M - 1;        // clamp: safe read, store guarded below
        aptr[i] = A + (size_t)gr * FDIM;
    }

    float acc[8][8];
#pragma unroll
    for (int i = 0; i < 8; ++i)
#pragma unroll
        for (int j = 0; j < 8; ++j) acc[i][j] = 0.f;

#pragma unroll 4
    for (int k = 0; k < 128; ++k) {
        float a[8], b[8];
#pragma unroll
        for (int i = 0; i < 8; ++i) a[i] = aptr[i][k];
        *(float4*)&b[0] = *(const float4*)&Ws[k][tx * 8];
        *(float4*)&b[4] = *(const float4*)&Ws[k][tx * 8 + 4];
#pragma unroll
        for (int i = 0; i < 8; ++i)
#pragma unroll
            for (int j = 0; j < 8; ++j) acc[i][j] = fmaf(a[i], b[j], acc[i][j]);
    }

#pragma unroll
    for (int i = 0; i < 8; ++i) {
        if (grow[i] < M) {
            float4 o0 = make_float4(acc[i][0], acc[i][1], acc[i][2], acc[i][3]);
            float4 o1 = make_float4(acc[i][4], acc[i][5], acc[i][6], acc[i][7]);
            *(float4*)&C[(size_t)grow[i] * FDIM + tx * 8]     = o0;
            *(float4*)&C[(size_t)grow[i] * FDIM + tx * 8 + 4] = o1;
        }
    }
}

// ---------------------------------------------------------------------------
// Kernel 3: SPMM. One wave (64 lanes) per output row; lane owns float2 of the
// 128 features. Rows sorted -> contiguous edge range [rp[r], rp[r+1]).
// out[r][:] = sum_e vals[e] * X[cols[e]][:] + bias  (+ optional relu)
// ---------------------------------------------------------------------------
template <int RELU>
__global__ __launch_bounds__(256) void spmm_k(const int* __restrict__ rp,
                                              const int* __restrict__ cols,
                                              const float* __restrict__ vals,
                                              const float* __restrict__ X,
                                              const float* __restrict__ bias,
                                              float* __restrict__ out, int N) {
    int wid  = (blockIdx.x * 256 + threadIdx.x) >> 6;   // one wave per row
    int lane = threadIdx.x & 63;
    if (wid >= N) return;
    int s = __builtin_amdgcn_readfirstlane(rp[wid]);
    int e = __builtin_amdgcn_readfirstlane(rp[wid + 1]);

    float ax0 = 0.f, ay0 = 0.f, ax1 = 0.f, ay1 = 0.f;
    int i = s;
    for (; i + 2 <= e; i += 2) {
        int   c0 = __builtin_amdgcn_readfirstlane(cols[i]);
        int   c1 = __builtin_amdgcn_readfirstlane(cols[i + 1]);
        float v0 = vals[i];
        float v1 = vals[i + 1];
        float2 x0 = *(const float2*)(X + (size_t)c0 * FDIM + lane * 2);
        float2 x1 = *(const float2*)(X + (size_t)c1 * FDIM + lane * 2);
        ax0 = fmaf(v0, x0.x, ax0); ay0 = fmaf(v0, x0.y, ay0);
        ax1 = fmaf(v1, x1.x, ax1); ay1 = fmaf(v1, x1.y, ay1);
    }
    if (i < e) {
        int   c0 = __builtin_amdgcn_readfirstlane(cols[i]);
        float v0 = vals[i];
        float2 x0 = *(const float2*)(X + (size_t)c0 * FDIM + lane * 2);
        ax0 = fmaf(v0, x0.x, ax0); ay0 = fmaf(v0, x0.y, ay0);
    }

    float2 b = *(const float2*)(bias + lane * 2);
    float ox = ax0 + ax1 + b.x;
    float oy = ay0 + ay1 + b.y;
    if (RELU) { ox = fmaxf(ox, 0.f); oy = fmaxf(oy, 0.f); }
    float2 o = make_float2(ox, oy);
    *(float2*)(out + (size_t)wid * FDIM + lane * 2) = o;
}

// ---------------------------------------------------------------------------
extern "C" void kernel_launch(void* const* d_in, const int* in_sizes, int n_in,
                              void* d_out, int out_size, void* d_ws, size_t ws_size,
                              hipStream_t stream) {
    const float* features = (const float*)d_in[0];
    const int*   adj_rows = (const int*)d_in[1];
    const int*   adj_cols = (const int*)d_in[2];
    const float* adj_vals = (const float*)d_in[3];
    const float* W1       = (const float*)d_in[4];
    const float* b1       = (const float*)d_in[5];
    const float* W2       = (const float*)d_in[6];
    const float* b2       = (const float*)d_in[7];

    const int N = in_sizes[0] / FDIM;    // 100000
    const int E = in_sizes[1];           // 3200000
    float* out = (float*)d_out;

    char* ws = (char*)d_ws;
    int* rp = (int*)ws;
    size_t rp_bytes = (((size_t)(N + 1) * sizeof(int)) + 255) & ~(size_t)255;
    float* XW = (float*)(ws + rp_bytes);                 // N*128 f32
    float* H  = XW + (size_t)N * FDIM;                   // N*128 f32

    // 1. CSR row_ptr
    build_row_ptr_k<<<(N + 256) / 256, 256, 0, stream>>>(adj_rows, E, N, rp);
    // 2. XW = X @ W1
    gemm_f32_k<<<(N + 127) / 128, 256, 0, stream>>>(features, W1, XW, N);
    // 3. H = relu(A_sp @ XW + b1)
    spmm_k<1><<<((size_t)N * 64 + 255) / 256, 256, 0, stream>>>(rp, adj_cols, adj_vals, XW, b1, H, N);
    // 4. XW = H @ W2   (buffer reuse)
    gemm_f32_k<<<(N + 127) / 128, 256, 0, stream>>>(H, W2, XW, N);
    // 5. out = A_sp @ XW + b2
    spmm_k<0><<<((size_t)N * 64 + 255) / 256, 256, 0, stream>>>(rp, adj_cols, adj_vals, XW, b2, out, N);
}

// Round 2
// 343.555 us; speedup vs baseline: 1.6119x; 1.6119x over previous
//
#include <hip/hip_runtime.h>
#include <type_traits>

#define FDIM 128

// ---------- bf16 helpers (manual, RNE) ----------
__device__ __forceinline__ uint16_t f2bf(float f) {
    uint32_t u = __float_as_uint(f);
    uint32_t r = (u + 0x7fffu + ((u >> 16) & 1u)) >> 16;
    return (uint16_t)r;
}
__device__ __forceinline__ uint32_t pack_bf16(float a, float b) {
    return (uint32_t)f2bf(a) | ((uint32_t)f2bf(b) << 16);
}
__device__ __forceinline__ float bflo(uint32_t u) { return __uint_as_float(u << 16); }
__device__ __forceinline__ float bfhi(uint32_t u) { return __uint_as_float(u & 0xffff0000u); }
__device__ __forceinline__ float bf2f(uint16_t h) { return __uint_as_float((uint32_t)h << 16); }

// ---------------------------------------------------------------------------
// Kernel 1: row_ptr[i] = lower_bound(rows, i), for i in [0, N]. rows sorted.
// ---------------------------------------------------------------------------
__global__ __launch_bounds__(256) void build_row_ptr_k(const int* __restrict__ rows,
                                                       int E, int N,
                                                       int* __restrict__ rp) {
    int i = blockIdx.x * 256 + threadIdx.x;
    if (i > N) return;
    int lo = 0, hi = E;
    while (lo < hi) {
        int mid = (lo + hi) >> 1;
        if (rows[mid] < i) lo = mid + 1; else hi = mid;
    }
    rp[i] = lo;
}

// ---------------------------------------------------------------------------
// Kernel 2: C[M x 128] = A[M x 128] @ W[128 x 128]; f32 vector-ALU compute.
// A is f32 (ABF=0) or bf16 (ABF=1); C stored bf16 (RNE). W staged f32 in LDS.
// 256 threads, 8x8 register tile each, block tile 128x128, full K resident.
// ---------------------------------------------------------------------------
template <int ABF>
__global__ __launch_bounds__(256) void gemm_k(const void* __restrict__ A_,
                                              const float* __restrict__ W,
                                              uint16_t* __restrict__ C, int M) {
    using AT = typename std::conditional<ABF, uint16_t, float>::type;
    const AT* A = (const AT*)A_;

    __shared__ float Ws[128][128];   // 65536 B
    const int t = threadIdx.x;
    const int row0 = blockIdx.x * 128;

#pragma unroll
    for (int i = 0; i < 16; ++i) {
        int f = t + i * 256;            // 0..4095
        int k = f >> 5;                 // W row
        int c = (f & 31) << 2;          // W col (float4)
        *(float4*)&Ws[k][c] = *(const float4*)&W[(k << 7) + c];
    }
    __syncthreads();

    const int ty = t >> 4;              // 0..15 -> 8 rows each
    const int tx = t & 15;              // 0..15 -> 8 cols each

    const AT* aptr[8];
    int grow[8];
#pragma unroll
    for (int i = 0; i < 8; ++i) {
        int gr = row0 + ty * 8 + i;
        grow[i] = gr;
        if (gr >= M) gr = M - 1;        // clamp: safe read, store guarded below
        aptr[i] = A + (size_t)gr * FDIM;
    }

    float acc[8][8];
#pragma unroll
    for (int i = 0; i < 8; ++i)
#pragma unroll
        for (int j = 0; j < 8; ++j) acc[i][j] = 0.f;

#pragma unroll 4
    for (int k = 0; k < 128; ++k) {
        float a[8], b[8];
#pragma unroll
        for (int i = 0; i < 8; ++i) {
            if constexpr (ABF) a[i] = bf2f(aptr[i][k]);
            else               a[i] = aptr[i][k];
        }
        *(float4*)&b[0] = *(const float4*)&Ws[k][tx * 8];
        *(float4*)&b[4] = *(const float4*)&Ws[k][tx * 8 + 4];
#pragma unroll
        for (int i = 0; i < 8; ++i)
#pragma unroll
            for (int j = 0; j < 8; ++j) acc[i][j] = fmaf(a[i], b[j], acc[i][j]);
    }

#pragma unroll
    for (int i = 0; i < 8; ++i) {
        if (grow[i] < M) {
            uint32_t p[4];
#pragma unroll
            for (int j = 0; j < 4; ++j)
                p[j] = pack_bf16(acc[i][2 * j], acc[i][2 * j + 1]);
            // byte addr = (row*128 + tx*8)*2 -> 16B aligned
            *(uint4*)&C[(size_t)grow[i] * FDIM + tx * 8] =
                make_uint4(p[0], p[1], p[2], p[3]);
        }
    }
}

// ---------------------------------------------------------------------------
// Kernel 3: SPMM over bf16 X. One wave per output row; lane owns 2 features
// (one dword = 2 bf16). f32 accumulate. Output bf16 (H) or f32 (final out).
// ---------------------------------------------------------------------------
template <int RELU, int OBF>
__global__ __launch_bounds__(256) void spmm_k(const int* __restrict__ rp,
                                              const int* __restrict__ cols,
                                              const float* __restrict__ vals,
                                              const uint32_t* __restrict__ X, // bf16x2
                                              const float* __restrict__ bias,
                                              void* __restrict__ out, int N) {
    int wid  = (blockIdx.x * 256 + threadIdx.x) >> 6;   // one wave per row
    int lane = threadIdx.x & 63;
    if (wid >= N) return;
    int s = __builtin_amdgcn_readfirstlane(rp[wid]);
    int e = __builtin_amdgcn_readfirstlane(rp[wid + 1]);

    float ax0 = 0.f, ay0 = 0.f, ax1 = 0.f, ay1 = 0.f;
    float ax2 = 0.f, ay2 = 0.f, ax3 = 0.f, ay3 = 0.f;
    int i = s;
    for (; i + 4 <= e; i += 4) {
        int c0 = __builtin_amdgcn_readfirstlane(cols[i]);
        int c1 = __builtin_amdgcn_readfirstlane(cols[i + 1]);
        int c2 = __builtin_amdgcn_readfirstlane(cols[i + 2]);
        int c3 = __builtin_amdgcn_readfirstlane(cols[i + 3]);
        float v0 = vals[i], v1 = vals[i + 1], v2 = vals[i + 2], v3 = vals[i + 3];
        uint32_t u0 = X[(size_t)c0 * 64 + lane];
        uint32_t u1 = X[(size_t)c1 * 64 + lane];
        uint32_t u2 = X[(size_t)c2 * 64 + lane];
        uint32_t u3 = X[(size_t)c3 * 64 + lane];
        ax0 = fmaf(v0, bflo(u0), ax0); ay0 = fmaf(v0, bfhi(u0), ay0);
        ax1 = fmaf(v1, bflo(u1), ax1); ay1 = fmaf(v1, bfhi(u1), ay1);
        ax2 = fmaf(v2, bflo(u2), ax2); ay2 = fmaf(v2, bfhi(u2), ay2);
        ax3 = fmaf(v3, bflo(u3), ax3); ay3 = fmaf(v3, bfhi(u3), ay3);
    }
    for (; i < e; ++i) {
        int c0 = __builtin_amdgcn_readfirstlane(cols[i]);
        float v0 = vals[i];
        uint32_t u0 = X[(size_t)c0 * 64 + lane];
        ax0 = fmaf(v0, bflo(u0), ax0); ay0 = fmaf(v0, bfhi(u0), ay0);
    }

    float ox = (ax0 + ax1) + (ax2 + ax3) + bias[lane * 2];
    float oy = (ay0 + ay1) + (ay2 + ay3) + bias[lane * 2 + 1];
    if (RELU) { ox = fmaxf(ox, 0.f); oy = fmaxf(oy, 0.f); }

    if constexpr (OBF) {
        ((uint32_t*)out)[(size_t)wid * 64 + lane] = pack_bf16(ox, oy);
    } else {
        *(float2*)((float*)out + (size_t)wid * FDIM + lane * 2) = make_float2(ox, oy);
    }
}

// ---------------------------------------------------------------------------
extern "C" void kernel_launch(void* const* d_in, const int* in_sizes, int n_in,
                              void* d_out, int out_size, void* d_ws, size_t ws_size,
                              hipStream_t stream) {
    const float* features = (const float*)d_in[0];
    const int*   adj_cols = (const int*)d_in[2];
    const float* adj_vals = (const float*)d_in[3];
    const float* W1       = (const float*)d_in[4];
    const float* b1       = (const float*)d_in[5];
    const float* W2       = (const float*)d_in[6];
    const float* b2       = (const float*)d_in[7];
    const int*   adj_rows = (const int*)d_in[1];

    const int N = in_sizes[0] / FDIM;    // 100000
    const int E = in_sizes[1];           // 3200000
    float* out = (float*)d_out;

    char* ws = (char*)d_ws;
    int* rp = (int*)ws;
    size_t rp_bytes = (((size_t)(N + 1) * sizeof(int)) + 255) & ~(size_t)255;
    uint16_t* XWb = (uint16_t*)(ws + rp_bytes);          // N*128 bf16 (25.6 MB)
    uint16_t* Hb  = XWb + (size_t)N * FDIM;              // N*128 bf16 (25.6 MB)

    // 1. CSR row_ptr
    build_row_ptr_k<<<(N + 256) / 256, 256, 0, stream>>>(adj_rows, E, N, rp);
    // 2. XWb = bf16(X @ W1)
    gemm_k<0><<<(N + 127) / 128, 256, 0, stream>>>((const void*)features, W1, XWb, N);
    // 3. Hb = bf16(relu(A_sp @ XWb + b1))
    spmm_k<1, 1><<<((size_t)N * 64 + 255) / 256, 256, 0, stream>>>(
        rp, adj_cols, adj_vals, (const uint32_t*)XWb, b1, (void*)Hb, N);
    // 4. XWb = bf16(Hb @ W2)   (buffer reuse: reads Hb, writes XWb)
    gemm_k<1><<<(N + 127) / 128, 256, 0, stream>>>((const void*)Hb, W2, XWb, N);
    // 5. out = A_sp @ XWb + b2   (f32 output)
    spmm_k<0, 0><<<((size_t)N * 64 + 255) / 256, 256, 0, stream>>>(
        rp, adj_cols, adj_vals, (const uint32_t*)XWb, b2, (void*)out, N);
}

// Round 3
// 291.006 us; speedup vs baseline: 1.9029x; 1.1806x over previous
//
#include <hip/hip_runtime.h>
#include <type_traits>

#define FDIM 128

typedef __attribute__((ext_vector_type(8))) short short8v;   // 8 bf16
typedef __attribute__((ext_vector_type(4))) float f32x4;

// ---------- bf16 helpers (manual, RNE) ----------
__device__ __forceinline__ uint16_t f2bf(float f) {
    uint32_t u = __float_as_uint(f);
    uint32_t r = (u + 0x7fffu + ((u >> 16) & 1u)) >> 16;
    return (uint16_t)r;
}
__device__ __forceinline__ uint32_t pack_bf16(float a, float b) {
    return (uint32_t)f2bf(a) | ((uint32_t)f2bf(b) << 16);
}
__device__ __forceinline__ float bflo(uint32_t u) { return __uint_as_float(u << 16); }
__device__ __forceinline__ float bfhi(uint32_t u) { return __uint_as_float(u & 0xffff0000u); }

// ---------------------------------------------------------------------------
// Kernel 1: row_ptr[i] = lower_bound(rows, i). rows sorted.
// ---------------------------------------------------------------------------
__global__ __launch_bounds__(256) void build_row_ptr_k(const int* __restrict__ rows,
                                                       int E, int N,
                                                       int* __restrict__ rp) {
    int i = blockIdx.x * 256 + threadIdx.x;
    if (i > N) return;
    int lo = 0, hi = E;
    while (lo < hi) {
        int mid = (lo + hi) >> 1;
        if (rows[mid] < i) lo = mid + 1; else hi = mid;
    }
    rp[i] = lo;
}

// ---------------------------------------------------------------------------
// Kernel 1b: Wt[n][k] = bf16(W[k][n]), 128x128. One-shot, trivial cost.
// ---------------------------------------------------------------------------
__global__ __launch_bounds__(256) void transpose_w_k(const float* __restrict__ W,
                                                     uint16_t* __restrict__ Wt) {
    int idx = blockIdx.x * 256 + threadIdx.x;   // 0..16383
    int k = idx >> 7, n = idx & 127;
    Wt[n * FDIM + k] = f2bf(W[k * FDIM + n]);
}

// ---------------------------------------------------------------------------
// Kernel 2: C[M x 128] = A[M x 128] @ W[128 x 128] via bf16 MFMA 16x16x32.
// A: f32 (ABF=0, converted on the fly) or bf16 (ABF=1). Wt is bf16 W^T
// ([n][k], 32KB, L1/L2-resident). C stored bf16.
// Block = 256 thr (4 waves), tile M=128 (32 rows/wave), N=128, K=128.
// A-frag: lane l holds A[row0 + (l&15)][ks*32 + (l>>4)*8 + 0..7]  (16B load)
// B-frag: lane l holds Wt[nf*16 + (l&15)][ks*32 + (l>>4)*8 + 0..7]
// D-frag: col = nf*16 + (l&15), row = (l>>4)*4 + j   (m89-verified)
// ---------------------------------------------------------------------------
template <int ABF>
__global__ __launch_bounds__(256) void gemm_mfma_k(const void* __restrict__ A_,
                                                   const uint16_t* __restrict__ Wt,
                                                   uint16_t* __restrict__ C, int M) {
    const int t = threadIdx.x;
    const int w = t >> 6;               // wave 0..3
    const int l = t & 63;
    const int row0 = blockIdx.x * 128 + w * 32;   // this wave's first row

    f32x4 acc[2][8];
#pragma unroll
    for (int mf = 0; mf < 2; ++mf)
#pragma unroll
        for (int nf = 0; nf < 8; ++nf) acc[mf][nf] = (f32x4)0.f;

    const int lr = l & 15;              // fragment row/col index
    const int kg = l >> 4;              // k-group 0..3

#pragma unroll
    for (int ks = 0; ks < 4; ++ks) {
        const int k0 = ks * 32 + kg * 8;
        short8v a[2];
#pragma unroll
        for (int mf = 0; mf < 2; ++mf) {
            int r = row0 + mf * 16 + lr;
            if (r >= M) r = M - 1;      // safe clamp; stores guarded
            if constexpr (ABF) {
                a[mf] = *(const short8v*)((const uint16_t*)A_ + (size_t)r * FDIM + k0);
            } else {
                const float* ap = (const float*)A_ + (size_t)r * FDIM + k0;
                float4 f0 = *(const float4*)(ap);
                float4 f1 = *(const float4*)(ap + 4);
                uint32_t p0 = pack_bf16(f0.x, f0.y), p1 = pack_bf16(f0.z, f0.w);
                uint32_t p2 = pack_bf16(f1.x, f1.y), p3 = pack_bf16(f1.z, f1.w);
                uint4 u = make_uint4(p0, p1, p2, p3);
                a[mf] = *(short8v*)&u;
            }
        }
#pragma unroll
        for (int nf = 0; nf < 8; ++nf) {
            short8v b = *(const short8v*)(Wt + (size_t)(nf * 16 + lr) * FDIM + k0);
            acc[0][nf] = __builtin_amdgcn_mfma_f32_16x16x32_bf16(a[0], b, acc[0][nf], 0, 0, 0);
            acc[1][nf] = __builtin_amdgcn_mfma_f32_16x16x32_bf16(a[1], b, acc[1][nf], 0, 0, 0);
        }
    }

    // store: pack adjacent-col pairs via shfl_xor(1); even-col lanes store dwords
    const int colpar = l & 1;
#pragma unroll
    for (int mf = 0; mf < 2; ++mf) {
#pragma unroll
        for (int nf = 0; nf < 8; ++nf) {
            int col = nf * 16 + lr;
#pragma unroll
            for (int j = 0; j < 4; ++j) {
                float v = acc[mf][nf][j];
                float pv = __shfl_xor(v, 1);
                int row = row0 + mf * 16 + kg * 4 + j;
                if (!colpar && row < M) {
                    *(uint32_t*)(C + (size_t)row * FDIM + col) = pack_bf16(v, pv);
                }
            }
        }
    }
}

// ---------------------------------------------------------------------------
// Kernel 3: SPMM over bf16 X. One wave per row; lane owns 2 features (1 dword).
// Unroll 8 with software-pipelined column prefetch. f32 accumulate.
// ---------------------------------------------------------------------------
template <int RELU, int OBF>
__global__ __launch_bounds__(256) void spmm_k(const int* __restrict__ rp,
                                              const int* __restrict__ cols,
                                              const float* __restrict__ vals,
                                              const uint32_t* __restrict__ X, // bf16x2
                                              const float* __restrict__ bias,
                                              void* __restrict__ out, int N) {
    int wid  = (blockIdx.x * 256 + threadIdx.x) >> 6;
    int lane = threadIdx.x & 63;
    if (wid >= N) return;
    int s = __builtin_amdgcn_readfirstlane(rp[wid]);
    int e = __builtin_amdgcn_readfirstlane(rp[wid + 1]);

    float ax[8], ay[8];
#pragma unroll
    for (int j = 0; j < 8; ++j) { ax[j] = 0.f; ay[j] = 0.f; }

    const int nfull = (e - s) >> 3;
    int i = s;
    int cc[8];

    if (nfull > 0) {
#pragma unroll
        for (int j = 0; j < 8; ++j) cc[j] = __builtin_amdgcn_readfirstlane(cols[i + j]);
        for (int g = 1; g < nfull; ++g) {
            int cn[8];
#pragma unroll
            for (int j = 0; j < 8; ++j) cn[j] = __builtin_amdgcn_readfirstlane(cols[i + 8 + j]);
            // gather + fma for current group (8 independent gathers in flight)
            uint32_t u[8];
#pragma unroll
            for (int j = 0; j < 8; ++j) u[j] = X[(size_t)cc[j] * 64 + lane];
#pragma unroll
            for (int j = 0; j < 8; ++j) {
                float v = vals[i + j];
                ax[j] = fmaf(v, bflo(u[j]), ax[j]);
                ay[j] = fmaf(v, bfhi(u[j]), ay[j]);
            }
#pragma unroll
            for (int j = 0; j < 8; ++j) cc[j] = cn[j];
            i += 8;
        }
        {
            uint32_t u[8];
#pragma unroll
            for (int j = 0; j < 8; ++j) u[j] = X[(size_t)cc[j] * 64 + lane];
#pragma unroll
            for (int j = 0; j < 8; ++j) {
                float v = vals[i + j];
                ax[j] = fmaf(v, bflo(u[j]), ax[j]);
                ay[j] = fmaf(v, bfhi(u[j]), ay[j]);
            }
            i += 8;
        }
    }
    // tail (< 8 edges)
    for (; i < e; ++i) {
        int c = __builtin_amdgcn_readfirstlane(cols[i]);
        float v = vals[i];
        uint32_t u = X[(size_t)c * 64 + lane];
        ax[0] = fmaf(v, bflo(u), ax[0]);
        ay[0] = fmaf(v, bfhi(u), ay[0]);
    }

    float ox = ((ax[0] + ax[1]) + (ax[2] + ax[3])) + ((ax[4] + ax[5]) + (ax[6] + ax[7]));
    float oy = ((ay[0] + ay[1]) + (ay[2] + ay[3])) + ((ay[4] + ay[5]) + (ay[6] + ay[7]));
    ox += bias[lane * 2];
    oy += bias[lane * 2 + 1];
    if (RELU) { ox = fmaxf(ox, 0.f); oy = fmaxf(oy, 0.f); }

    if constexpr (OBF) {
        ((uint32_t*)out)[(size_t)wid * 64 + lane] = pack_bf16(ox, oy);
    } else {
        *(float2*)((float*)out + (size_t)wid * FDIM + lane * 2) = make_float2(ox, oy);
    }
}

// ---------------------------------------------------------------------------
extern "C" void kernel_launch(void* const* d_in, const int* in_sizes, int n_in,
                              void* d_out, int out_size, void* d_ws, size_t ws_size,
                              hipStream_t stream) {
    const float* features = (const float*)d_in[0];
    const int*   adj_rows = (const int*)d_in[1];
    const int*   adj_cols = (const int*)d_in[2];
    const float* adj_vals = (const float*)d_in[3];
    const float* W1       = (const float*)d_in[4];
    const float* b1       = (const float*)d_in[5];
    const float* W2       = (const float*)d_in[6];
    const float* b2       = (const float*)d_in[7];

    const int N = in_sizes[0] / FDIM;    // 100000
    const int E = in_sizes[1];           // 3200000
    float* out = (float*)d_out;

    char* ws = (char*)d_ws;
    int* rp = (int*)ws;
    size_t rp_bytes = (((size_t)(N + 1) * sizeof(int)) + 255) & ~(size_t)255;
    uint16_t* XWb = (uint16_t*)(ws + rp_bytes);          // N*128 bf16 (25.6 MB)
    uint16_t* Hb  = XWb + (size_t)N * FDIM;              // N*128 bf16 (25.6 MB)
    uint16_t* W1t = Hb + (size_t)N * FDIM;               // 128*128 bf16 (32 KB)
    uint16_t* W2t = W1t + FDIM * FDIM;                   // 128*128 bf16 (32 KB)

    const int nblk = (N + 127) / 128;

    // 1. CSR row_ptr + W transposes (independent, tiny)
    build_row_ptr_k<<<(N + 256) / 256, 256, 0, stream>>>(adj_rows, E, N, rp);
    transpose_w_k<<<64, 256, 0, stream>>>(W1, W1t);
    transpose_w_k<<<64, 256, 0, stream>>>(W2, W2t);
    // 2. XWb = bf16(X @ W1)   (MFMA)
    gemm_mfma_k<0><<<nblk, 256, 0, stream>>>((const void*)features, W1t, XWb, N);
    // 3. Hb = bf16(relu(A_sp @ XWb + b1))
    spmm_k<1, 1><<<((size_t)N * 64 + 255) / 256, 256, 0, stream>>>(
        rp, adj_cols, adj_vals, (const uint32_t*)XWb, b1, (void*)Hb, N);
    // 4. XWb = bf16(Hb @ W2)   (MFMA, buffer reuse)
    gemm_mfma_k<1><<<nblk, 256, 0, stream>>>((const void*)Hb, W2t, XWb, N);
    // 5. out = A_sp @ XWb + b2   (f32 output)
    spmm_k<0, 0><<<((size_t)N * 64 + 255) / 256, 256, 0, stream>>>(
        rp, adj_cols, adj_vals, (const uint32_t*)XWb, b2, (void*)out, N);
}